// Round 1
// baseline (1335.669 us; speedup 1.0000x reference)
//
#include <hip/hip_runtime.h>
#include <hip/hip_bf16.h>

// NonLocalBlockND with positional encoding, MI355X (gfx950).
// Pipeline: proj_theta (fp32 GEMM -> f16 tT[n][256], BN+ReLU fused)
//           proj_g     (fp32 GEMM -> f16 gc[c][NP], c-major)
//           attn       (flash attention, f16 MFMA 16x16x32, m-split x4 partials)
//           merge      (combine 4 softmax partials -> yT[n][512] f32)
//           out_gemm   (fp32 GEMM -> out[o][9409])
// Workspace layout (bytes):
//   tT    @ 0          : 9472*256*2  = 4,849,664
//   gc    @ 4,849,664  : 512*9472*2  = 9,699,328
//   part  @ 14,548,992 : 148*4*64*512*2 = 38,797,312
//   stats @ 53,346,304 : 148*4*64*2*4   = 303,104
//   yT    @ 53,649,408 : 9472*512*4  = 19,398,656
//   total 73,048,064 B (~73 MB)

#define NTOK 9409
#define NP   9472
#define C1V  256
#define C2V  512
#define KD   1024
#define NMT  295   // ceil(9409/32) m-tiles

typedef _Float16 f16;
typedef _Float16 f16x8 __attribute__((ext_vector_type(8)));
typedef _Float16 f16x4 __attribute__((ext_vector_type(4)));
typedef float    f32x4 __attribute__((ext_vector_type(4)));

__device__ __forceinline__ float xmix_load(const float* __restrict__ x,
                                           const float* __restrict__ pos,
                                           int k, int n) {
  return (k < 512) ? x[k * NTOK + n] : pos[(k - 512) * NTOK + n];
}

// ---------------------------------------------------------------------------
// proj_theta: tT[n][o] = relu( (W_theta@xmix + b) * gamma/sqrt(1+eps) + beta )
// fp32 GEMM, tile 128n x 64o, BK=16, 256 threads, 8x4 micro-tile.
// grid: (o_tiles=4, n_tiles=74)
// ---------------------------------------------------------------------------
__global__ __launch_bounds__(256) void proj_theta_kernel(
    const float* __restrict__ x, const float* __restrict__ pos,
    const float* __restrict__ wt, const float* __restrict__ bt,
    const float* __restrict__ gam, const float* __restrict__ bet,
    f16* __restrict__ tT) {
  __shared__ float As[16][128];  // [k][n]
  __shared__ float Bs[16][64];   // [k][o]
  const int n0 = blockIdx.y * 128;
  const int o0 = blockIdx.x * 64;
  const int tid = threadIdx.x;
  const int tx = tid & 15, ty = tid >> 4;
  float acc[8][4];
#pragma unroll
  for (int i = 0; i < 8; ++i)
#pragma unroll
    for (int j = 0; j < 4; ++j) acc[i][j] = 0.f;

  for (int k0 = 0; k0 < KD; k0 += 16) {
#pragma unroll
    for (int i = 0; i < 8; ++i) {
      int ci = i * 256 + tid;
      int kl = ci >> 7, nl = ci & 127;
      int n = n0 + nl;
      As[kl][nl] = (n < NTOK) ? xmix_load(x, pos, k0 + kl, n) : 0.f;
    }
#pragma unroll
    for (int i = 0; i < 4; ++i) {
      int ci = i * 256 + tid;
      int kl = ci & 15, ol = ci >> 4;
      Bs[kl][ol] = wt[(o0 + ol) * KD + k0 + kl];
    }
    __syncthreads();
#pragma unroll
    for (int kk = 0; kk < 16; ++kk) {
      f32x4 a0 = *(const f32x4*)&As[kk][ty * 8];
      f32x4 a1 = *(const f32x4*)&As[kk][ty * 8 + 4];
      f32x4 b  = *(const f32x4*)&Bs[kk][tx * 4];
#pragma unroll
      for (int i = 0; i < 4; ++i)
#pragma unroll
        for (int j = 0; j < 4; ++j) {
          acc[i][j]     += a0[i] * b[j];
          acc[i + 4][j] += a1[i] * b[j];
        }
    }
    __syncthreads();
  }
  const float inv = 0.9999950000374997f;  // 1/sqrt(1+1e-5)
#pragma unroll
  for (int i = 0; i < 8; ++i) {
    int n = n0 + ty * 8 + i;
    if (n >= NTOK) continue;
    f16x4 st;
#pragma unroll
    for (int j = 0; j < 4; ++j) {
      int o = o0 + tx * 4 + j;
      float v = acc[i][j] + bt[o];
      v = v * (gam[o] * inv) + bet[o];
      st[j] = (f16)fmaxf(v, 0.f);
    }
    *(f16x4*)(tT + (size_t)n * C1V + o0 + tx * 4) = st;
  }
}

// ---------------------------------------------------------------------------
// proj_g: gc[c][n] = W_g@xmix + b_g   (c-major, padded row NP)
// fp32 GEMM, tile 128c x 64n. grid: (n_tiles=148, c_tiles=4)
// ---------------------------------------------------------------------------
__global__ __launch_bounds__(256) void proj_g_kernel(
    const float* __restrict__ x, const float* __restrict__ pos,
    const float* __restrict__ wg, const float* __restrict__ bg,
    f16* __restrict__ gc) {
  __shared__ float As[16][128];  // [k][c]
  __shared__ float Bs[16][64];   // [k][n]
  const int c0 = blockIdx.y * 128;
  const int n0 = blockIdx.x * 64;
  const int tid = threadIdx.x;
  const int tx = tid & 15, ty = tid >> 4;
  float acc[8][4];
#pragma unroll
  for (int i = 0; i < 8; ++i)
#pragma unroll
    for (int j = 0; j < 4; ++j) acc[i][j] = 0.f;

  for (int k0 = 0; k0 < KD; k0 += 16) {
#pragma unroll
    for (int i = 0; i < 8; ++i) {
      int ci = i * 256 + tid;
      int kl = ci & 15, cl = ci >> 4;
      As[kl][cl] = wg[(c0 + cl) * KD + k0 + kl];
    }
#pragma unroll
    for (int i = 0; i < 4; ++i) {
      int ci = i * 256 + tid;
      int kl = ci >> 6, nl = ci & 63;
      int n = n0 + nl;
      Bs[kl][nl] = (n < NTOK) ? xmix_load(x, pos, k0 + kl, n) : 0.f;
    }
    __syncthreads();
#pragma unroll
    for (int kk = 0; kk < 16; ++kk) {
      f32x4 a0 = *(const f32x4*)&As[kk][ty * 8];
      f32x4 a1 = *(const f32x4*)&As[kk][ty * 8 + 4];
      f32x4 b  = *(const f32x4*)&Bs[kk][tx * 4];
#pragma unroll
      for (int i = 0; i < 4; ++i)
#pragma unroll
        for (int j = 0; j < 4; ++j) {
          acc[i][j]     += a0[i] * b[j];
          acc[i + 4][j] += a1[i] * b[j];
        }
    }
    __syncthreads();
  }
  const bool full = (n0 + 64 <= NTOK);
#pragma unroll
  for (int i = 0; i < 8; ++i) {
    int c = c0 + ty * 8 + i;
    float bias = bg[c];
    if (full) {
      f16x4 st;
#pragma unroll
      for (int j = 0; j < 4; ++j) st[j] = (f16)(acc[i][j] + bias);
      *(f16x4*)(gc + (size_t)c * NP + n0 + tx * 4) = st;
    } else {
#pragma unroll
      for (int j = 0; j < 4; ++j) {
        int n = n0 + tx * 4 + j;
        if (n < NTOK) gc[(size_t)c * NP + n] = (f16)(acc[i][j] + bias);
      }
    }
  }
}

// ---------------------------------------------------------------------------
// attn: flash attention partials. Block = 4 row-waves (64 q-rows) x m-quarter q.
// bid = rb*4 + q  (rb: 148 row-blocks, q: 4 m-split) -> q-quarter per XCD.
// Each wave: 16 rows. Per m-tile (32 keys): stage K[32][256] + V[512][32] in
// LDS (XOR-swizzled), QK^T via mfma_f32_16x16x32_f16, online softmax (j-reg =
// row within 16-lane group), P->LDS->A-frag, PV accumulate 32 c-frags.
// Outputs partial (acc/L) f16 + (M, L) stats per row.
// ---------------------------------------------------------------------------
__global__ __launch_bounds__(256, 2) void attn_kernel(
    const f16* __restrict__ tT, const f16* __restrict__ gc,
    f16* __restrict__ part, float* __restrict__ stats) {
  __shared__ uint4 lds[53248 / 16];  // Ks 16KB | Vs 32KB | P 4x1KB
  char* KsB = (char*)lds;
  char* VsB = (char*)lds + 16384;
  const int bid = blockIdx.x;
  const int rb = bid >> 2, q = bid & 3;
  const int tid = threadIdx.x;
  const int w = tid >> 6;
  const int lane = tid & 63;
  const int l15 = lane & 15, l4 = lane >> 4;
  f16* Pw = (f16*)((char*)lds + 49152 + w * 1024);

  // Q fragments: A-frag lane layout row=l15, k=l4*8+j  (held for all 8 k-steps)
  const int nrow = rb * 64 + w * 16 + l15;
  f16x8 Qf[8];
  const f16* qp = tT + (size_t)nrow * C1V + l4 * 8;
#pragma unroll
  for (int kk = 0; kk < 8; ++kk) Qf[kk] = *(const f16x8*)(qp + kk * 32);

  f32x4 acc[32];
#pragma unroll
  for (int cf = 0; cf < 32; ++cf) acc[cf] = (f32x4){0.f, 0.f, 0.f, 0.f};
  float M[4] = {-1e30f, -1e30f, -1e30f, -1e30f};
  float L[4] = {0.f, 0.f, 0.f, 0.f};

  for (int u = 0;; ++u) {
    const int t = 8 * (u >> 1) + 2 * q + (u & 1);  // pair-chunked quarters (V line-aligned)
    if (t >= NMT) break;
    const int m0 = t * 32;
    __syncthreads();
    // --- stage K tile [32 m][256 k], row 512B, slot-XOR swizzle by m&7 ---
    {
      const f16* ksrc = tT + (size_t)m0 * C1V;
#pragma unroll
      for (int i = 0; i < 4; ++i) {
        int ci = i * 256 + tid;
        int m = ci >> 5, s = ci & 31;
        f16x8 v = *(const f16x8*)(ksrc + ci * 8);
        *(f16x8*)(KsB + m * 512 + ((s ^ (m & 7)) << 4)) = v;
      }
      // --- stage V tile [512 c][32 m], pair-row (128B) XOR swizzle ---
#pragma unroll
      for (int i = 0; i < 8; ++i) {
        int ci = i * 256 + tid;
        int c = ci >> 2, s = ci & 3;
        f16x8 v = *(const f16x8*)(gc + (size_t)c * NP + m0 + s * 8);
        int sl = (((c & 1) << 2) | s) ^ ((c >> 1) & 7);
        *(f16x8*)(VsB + (c >> 1) * 128 + (sl << 4)) = v;
      }
    }
    __syncthreads();
    // --- QK^T: S[16 r][32 m] in two 16x16 D-frags ---
    f32x4 s0 = {0.f, 0.f, 0.f, 0.f}, s1 = {0.f, 0.f, 0.f, 0.f};
    const int kx = l15 & 7;
#pragma unroll
    for (int kk = 0; kk < 8; ++kk) {
      int sr = kk * 4 + l4;
      f16x8 kb0 = *(const f16x8*)(KsB + l15 * 512 + ((sr ^ kx) << 4));
      f16x8 kb1 = *(const f16x8*)(KsB + (16 + l15) * 512 + ((sr ^ kx) << 4));
      s0 = __builtin_amdgcn_mfma_f32_16x16x32_f16(Qf[kk], kb0, s0, 0, 0, 0);
      s1 = __builtin_amdgcn_mfma_f32_16x16x32_f16(Qf[kk], kb1, s1, 0, 0, 0);
    }
    float sv0[4], sv1[4];
#pragma unroll
    for (int j = 0; j < 4; ++j) { sv0[j] = s0[j] * 0.0625f; sv1[j] = s1[j] * 0.0625f; }
    if (m0 + 32 > NTOK) {  // mask padded keys (last tile only)
      if (m0 + l15 >= NTOK)
#pragma unroll
        for (int j = 0; j < 4; ++j) sv0[j] = -1e30f;
      if (m0 + 16 + l15 >= NTOK)
#pragma unroll
        for (int j = 0; j < 4; ++j) sv1[j] = -1e30f;
    }
    // row max across the 16 lanes of this quarter-group (cols m)
    float rm[4];
#pragma unroll
    for (int j = 0; j < 4; ++j) rm[j] = fmaxf(sv0[j], sv1[j]);
#pragma unroll
    for (int d = 1; d <= 8; d <<= 1)
#pragma unroll
      for (int j = 0; j < 4; ++j) rm[j] = fmaxf(rm[j], __shfl_xor(rm[j], d));
    int grow = 0;
#pragma unroll
    for (int j = 0; j < 4; ++j) grow |= (rm[j] > M[j]) ? 1 : 0;
    if (__any(grow)) {  // rescale only when running max grows (T13-lite)
#pragma unroll
      for (int j = 0; j < 4; ++j) {
        float Mn = fmaxf(M[j], rm[j]);
        float al = __expf(M[j] - Mn);
        M[j] = Mn;
        L[j] *= al;
#pragma unroll
        for (int cf = 0; cf < 32; ++cf) acc[cf][j] *= al;
      }
    }
    float p0[4], p1[4], rs[4];
#pragma unroll
    for (int j = 0; j < 4; ++j) {
      p0[j] = __expf(sv0[j] - M[j]);
      p1[j] = __expf(sv1[j] - M[j]);
      rs[j] = p0[j] + p1[j];
    }
#pragma unroll
    for (int d = 1; d <= 8; d <<= 1)
#pragma unroll
      for (int j = 0; j < 4; ++j) rs[j] += __shfl_xor(rs[j], d);
#pragma unroll
    for (int j = 0; j < 4; ++j) L[j] += rs[j];
    // P (D-layout) -> per-wave LDS -> A-frag layout
#pragma unroll
    for (int j = 0; j < 4; ++j) {
      int r = l4 * 4 + j;
      Pw[r * 32 + l15] = (f16)p0[j];
      Pw[r * 32 + 16 + l15] = (f16)p1[j];
    }
    asm volatile("s_waitcnt lgkmcnt(0)" ::: "memory");
    __builtin_amdgcn_sched_barrier(0);
    f16x8 pa = *(const f16x8*)(Pw + l15 * 32 + l4 * 8);
    // --- PV: 32 c-frags, B-frag = V[m][c] from swizzled Vs ---
#pragma unroll
    for (int cf = 0; cf < 32; ++cf) {
      int c = cf * 16 + l15;
      int sl = (((c & 1) << 2) | l4) ^ ((c >> 1) & 7);
      f16x8 vb = *(const f16x8*)(VsB + (c >> 1) * 128 + (sl << 4));
      acc[cf] = __builtin_amdgcn_mfma_f32_16x16x32_f16(pa, vb, acc[cf], 0, 0, 0);
    }
  }
  // --- epilogue: normalized partial + stats ---
  float rinv[4];
#pragma unroll
  for (int j = 0; j < 4; ++j) rinv[j] = 1.0f / L[j];
  const int prow = (rb * 4 + q) * 64 + w * 16 + l4 * 4;
  if (l15 == 0) {
#pragma unroll
    for (int j = 0; j < 4; ++j) {
      stats[(prow + j) * 2] = M[j];
      stats[(prow + j) * 2 + 1] = L[j];
    }
  }
#pragma unroll
  for (int cf = 0; cf < 32; ++cf)
#pragma unroll
    for (int j = 0; j < 4; ++j)
      part[(size_t)(prow + j) * C2V + cf * 16 + l15] = (f16)(acc[cf][j] * rinv[j]);
}

// ---------------------------------------------------------------------------
// merge: combine 4 m-split partials per row -> yT[n][512] f32
// ---------------------------------------------------------------------------
__global__ __launch_bounds__(256) void merge_kernel(
    const f16* __restrict__ part, const float* __restrict__ stats,
    float* __restrict__ yT) {
  const int n = blockIdx.x;
  const int rb = n >> 6, rl = n & 63;
  float Mq[4], Lq[4];
#pragma unroll
  for (int qq = 0; qq < 4; ++qq) {
    int pr = (rb * 4 + qq) * 64 + rl;
    Mq[qq] = stats[pr * 2];
    Lq[qq] = stats[pr * 2 + 1];
  }
  float Ms = fmaxf(fmaxf(Mq[0], Mq[1]), fmaxf(Mq[2], Mq[3]));
  float wq[4], lt = 0.f;
#pragma unroll
  for (int qq = 0; qq < 4; ++qq) {
    wq[qq] = __expf(Mq[qq] - Ms) * Lq[qq];
    lt += wq[qq];
  }
  float inv = 1.f / lt;
  const int tid = threadIdx.x;
  for (int c = tid; c < C2V; c += 256) {
    float y = 0.f;
#pragma unroll
    for (int qq = 0; qq < 4; ++qq)
      y += wq[qq] * (float)part[(size_t)((rb * 4 + qq) * 64 + rl) * C2V + c];
    yT[(size_t)n * C2V + c] = y * inv;
  }
}

// ---------------------------------------------------------------------------
// out_gemm: out[o][n] = b_out[o] + sum_c w_out[o][c] * yT[n][c]
// fp32 GEMM, tile 128o x 64n, K=512. grid: (n_tiles=148, o_tiles=4)
// ---------------------------------------------------------------------------
__global__ __launch_bounds__(256) void out_gemm_kernel(
    const float* __restrict__ yT, const float* __restrict__ wo,
    const float* __restrict__ bo, float* __restrict__ out) {
  __shared__ float As[16][128];  // [kc][o]
  __shared__ float Bs[16][64];   // [kc][n]
  const int o0 = blockIdx.y * 128;
  const int n0 = blockIdx.x * 64;
  const int tid = threadIdx.x;
  const int tx = tid & 15, ty = tid >> 4;
  float acc[8][4];
#pragma unroll
  for (int i = 0; i < 8; ++i)
#pragma unroll
    for (int j = 0; j < 4; ++j) acc[i][j] = 0.f;

  for (int k0 = 0; k0 < C2V; k0 += 16) {
#pragma unroll
    for (int i = 0; i < 8; ++i) {
      int ci = i * 256 + tid;
      int kl = ci & 15, ol = ci >> 4;
      As[kl][ol] = wo[(o0 + ol) * C2V + k0 + kl];
    }
#pragma unroll
    for (int i = 0; i < 4; ++i) {
      int ci = i * 256 + tid;
      int kl = ci & 15, nl = ci >> 4;
      int n = n0 + nl;
      Bs[kl][nl] = (n < NTOK) ? yT[(size_t)n * C2V + k0 + kl] : 0.f;
    }
    __syncthreads();
#pragma unroll
    for (int kk = 0; kk < 16; ++kk) {
      f32x4 a0 = *(const f32x4*)&As[kk][ty * 8];
      f32x4 a1 = *(const f32x4*)&As[kk][ty * 8 + 4];
      f32x4 b  = *(const f32x4*)&Bs[kk][tx * 4];
#pragma unroll
      for (int i = 0; i < 4; ++i)
#pragma unroll
        for (int j = 0; j < 4; ++j) {
          acc[i][j]     += a0[i] * b[j];
          acc[i + 4][j] += a1[i] * b[j];
        }
    }
    __syncthreads();
  }
#pragma unroll
  for (int i = 0; i < 8; ++i) {
    int o = o0 + ty * 8 + i;
    float bias = bo[o];
#pragma unroll
    for (int j = 0; j < 4; ++j) {
      int n = n0 + tx * 4 + j;
      if (n < NTOK) out[(size_t)o * NTOK + n] = acc[i][j] + bias;
    }
  }
}

// ---------------------------------------------------------------------------
extern "C" void kernel_launch(void* const* d_in, const int* in_sizes, int n_in,
                              void* d_out, int out_size, void* d_ws, size_t ws_size,
                              hipStream_t stream) {
  const float* x   = (const float*)d_in[0];
  const float* pos = (const float*)d_in[1];
  const float* wt  = (const float*)d_in[2];
  const float* bt  = (const float*)d_in[3];
  const float* gam = (const float*)d_in[4];
  const float* bet = (const float*)d_in[5];
  const float* wg  = (const float*)d_in[6];
  const float* bg  = (const float*)d_in[7];
  const float* wo  = (const float*)d_in[8];
  const float* bo  = (const float*)d_in[9];
  float* out = (float*)d_out;

  char* ws = (char*)d_ws;
  f16*   tT    = (f16*)(ws);
  f16*   gc    = (f16*)(ws + 4849664);
  f16*   part  = (f16*)(ws + 14548992);
  float* stats = (float*)(ws + 53346304);
  float* yT    = (float*)(ws + 53649408);

  proj_theta_kernel<<<dim3(4, 74), dim3(256), 0, stream>>>(x, pos, wt, bt, gam, bet, tT);
  proj_g_kernel<<<dim3(148, 4), dim3(256), 0, stream>>>(x, pos, wg, bg, gc);
  attn_kernel<<<dim3(592), dim3(256), 0, stream>>>(tT, gc, part, stats);
  merge_kernel<<<dim3(NTOK), dim3(256), 0, stream>>>(part, stats, yT);
  out_gemm_kernel<<<dim3(148, 4), dim3(256), 0, stream>>>(yT, wo, bo, out);
}